// Round 2
// baseline (1242.214 us; speedup 1.0000x reference)
//
#include <hip/hip_runtime.h>
#include <hip/hip_bf16.h>

#define N_NODES 100000
#define N_EDGES 20000
#define NNZ     1600000
#define D       128
#define STAR    64
#define NEG_SLOPE 0.2f

// counting-sort partition machinery
#define NBLK    80          // blocks owning incidence chunks
#define CHUNK   20000       // NNZ / NBLK
#define BINS_PP 16384       // bins per LDS pass (64 KB static LDS)

// ---------------------------------------------------------------------------
// K1: fused node GEMM:  [X_init | X_feat] = X @ [Wx^T | Wv^T] + bias
// M=100000, N=256 (cols 0..127 -> X_init (d_out), 128..255 -> X_feat (ws))
// 64x64x16 tile, 256 threads, 4x4 microtile. fp32 VALU.
// ---------------------------------------------------------------------------
#define BM 64
#define BN 64
#define BK 16

__global__ __launch_bounds__(256) void k_node_gemm(
    const float* __restrict__ X,
    const float* __restrict__ Wx, const float* __restrict__ Wxb,
    const float* __restrict__ Wv, const float* __restrict__ Wvb,
    float* __restrict__ Xinit, float* __restrict__ Xfeat)
{
    __shared__ float As[BK][BM + 4];
    __shared__ float Bs[BK][BN + 4];
    const int tid = threadIdx.x;
    const int bm = blockIdx.x * BM;
    const int bn = blockIdx.y * BN;        // 0,64,128,192
    const int lr = tid >> 2;               // 0..63  (row in tile for loads)
    const int lk = (tid & 3) * 4;          // 0,4,8,12 (k offset for loads)
    const int tx = tid & 15, ty = tid >> 4;

    float acc[4][4] = {};

    for (int k0 = 0; k0 < D; k0 += BK) {
        // A tile: X[bm+lr][k0+lk .. +3]
        float4 av = make_float4(0.f, 0.f, 0.f, 0.f);
        int node = bm + lr;
        if (node < N_NODES)
            av = *(const float4*)(X + (size_t)node * D + k0 + lk);
        As[lk + 0][lr] = av.x; As[lk + 1][lr] = av.y;
        As[lk + 2][lr] = av.z; As[lk + 3][lr] = av.w;
        // B tile: row d = bn+lr of Wcat (Wx rows 0..127, Wv rows 128..255)
        int dd = bn + lr;
        const float* wsrc = (dd < D) ? (Wx + (size_t)dd * D)
                                     : (Wv + (size_t)(dd - D) * D);
        float4 bv = *(const float4*)(wsrc + k0 + lk);
        Bs[lk + 0][lr] = bv.x; Bs[lk + 1][lr] = bv.y;
        Bs[lk + 2][lr] = bv.z; Bs[lk + 3][lr] = bv.w;
        __syncthreads();
        #pragma unroll
        for (int kk = 0; kk < BK; ++kk) {
            float4 af = *(const float4*)&As[kk][ty * 4];
            float4 bf = *(const float4*)&Bs[kk][tx * 4];
            float a[4] = {af.x, af.y, af.z, af.w};
            float b[4] = {bf.x, bf.y, bf.z, bf.w};
            #pragma unroll
            for (int r = 0; r < 4; ++r)
                #pragma unroll
                for (int c = 0; c < 4; ++c)
                    acc[r][c] = fmaf(a[r], b[c], acc[r][c]);
        }
        __syncthreads();
    }

    // epilogue
    const int gcol = bn + tx * 4;
    const bool isInit = (gcol < D);
    const int cc = isInit ? gcol : (gcol - D);
    const float* bias = isInit ? Wxb : Wvb;
    float* dst = isInit ? Xinit : Xfeat;
    float4 bb = *(const float4*)(bias + cc);
    #pragma unroll
    for (int r = 0; r < 4; ++r) {
        int node = bm + ty * 4 + r;
        if (node < N_NODES) {
            float4 o = make_float4(acc[r][0] + bb.x, acc[r][1] + bb.y,
                                   acc[r][2] + bb.z, acc[r][3] + bb.w);
            *(float4*)(dst + (size_t)node * D + cc) = o;
        }
    }
}

// ---------------------------------------------------------------------------
// K2: score[n] = leaky_relu(X_feat[n,:] . a_w)  — one wave per node
// ---------------------------------------------------------------------------
__global__ __launch_bounds__(256) void k_score(
    const float* __restrict__ Xfeat, const float* __restrict__ aw,
    float* __restrict__ ls)
{
    const int wave = threadIdx.x >> 6, lane = threadIdx.x & 63;
    const int node = blockIdx.x * 4 + wave;
    if (node >= N_NODES) return;
    float2 x = *(const float2*)(Xfeat + (size_t)node * D + lane * 2);
    float2 a = *(const float2*)(aw + lane * 2);
    float s = x.x * a.x + x.y * a.y;
    #pragma unroll
    for (int off = 32; off > 0; off >>= 1) s += __shfl_down(s, off, 64);
    if (lane == 0) ls[node] = (s > 0.f) ? s : NEG_SLOPE * s;
}

// ---------------------------------------------------------------------------
// K3: per-(block,bin) partial histograms via LDS — NO global atomics.
// Block b owns incidences [b*CHUNK, (b+1)*CHUNK). Bins processed in
// BINS_PP-wide passes (64 KB LDS). part layout: part[b*nbins + bin].
// ---------------------------------------------------------------------------
__global__ __launch_bounds__(256) void k_part(
    const int* __restrict__ keys, int nbins, int* __restrict__ part)
{
    __shared__ int h[BINS_PP];
    const int b = blockIdx.x;
    const int i0 = b * CHUNK;
    for (int c0 = 0; c0 < nbins; c0 += BINS_PP) {
        const int nb = min(BINS_PP, nbins - c0);
        for (int t = threadIdx.x; t < nb; t += 256) h[t] = 0;
        __syncthreads();
        for (int i = threadIdx.x; i < CHUNK; i += 256) {
            int c = keys[i0 + i] - c0;
            if (c >= 0 && c < nb) atomicAdd(&h[c], 1);   // LDS atomic (on-CU)
        }
        __syncthreads();
        for (int t = threadIdx.x; t < nb; t += 256)
            part[(size_t)b * nbins + c0 + t] = h[t];
        __syncthreads();
    }
}

// ---------------------------------------------------------------------------
// K4: in-place exclusive prefix over blocks per bin; emits per-bin totals.
// One thread per bin; reads coalesced across threads for each b.
// ---------------------------------------------------------------------------
__global__ __launch_bounds__(256) void k_tot_base(
    int* __restrict__ part, int nbins, int* __restrict__ tot)
{
    int bin = blockIdx.x * 256 + threadIdx.x;
    if (bin >= nbins) return;
    int run = 0;
    for (int b = 0; b < NBLK; ++b) {
        size_t idx = (size_t)b * nbins + bin;
        int v = part[idx];
        part[idx] = run;        // exclusive prefix over blocks
        run += v;
    }
    tot[bin] = run;
}

// ---------------------------------------------------------------------------
// Single-block exclusive scan (n up to ~100k): per-thread serial chunks +
// Hillis-Steele over 1024 partials. off has n+1 entries (off[n] = total).
// ---------------------------------------------------------------------------
__global__ __launch_bounds__(1024) void k_scan(
    const int* __restrict__ cnt, int* __restrict__ off, int n)
{
    __shared__ int sums[1024];
    const int tid = threadIdx.x;
    const int chunk = (n + 1023) / 1024;
    const int start = tid * chunk;
    const int end = min(start + chunk, n);
    int s = 0;
    for (int i = start; i < end; ++i) s += cnt[i];
    sums[tid] = s;
    __syncthreads();
    #pragma unroll
    for (int dstep = 1; dstep < 1024; dstep <<= 1) {
        int mine = sums[tid];
        int other = (tid >= dstep) ? sums[tid - dstep] : 0;
        __syncthreads();
        sums[tid] = mine + other;
        __syncthreads();
    }
    int run = (tid > 0) ? sums[tid - 1] : 0;
    for (int i = start; i < end; ++i) { off[i] = run; run += cnt[i]; }
    if (tid == 0) off[n] = sums[1023];
}

// ---------------------------------------------------------------------------
// K5a: scatter incidences into edge-CSR. LDS cursors seeded from the
// per-(block,bin) exclusive prefixes — only LDS atomics.
// epairs[pos] = (v, w_raw = exp(leaky_score[v])).
// ---------------------------------------------------------------------------
__global__ __launch_bounds__(256) void k_scatter_e(
    const int* __restrict__ V, const int* __restrict__ E,
    const float* __restrict__ ls, const int* __restrict__ eoff,
    const int* __restrict__ part, int2* __restrict__ epairs)
{
    __shared__ int cur[BINS_PP];
    const int b = blockIdx.x;
    const int i0 = b * CHUNK;
    for (int c0 = 0; c0 < N_EDGES; c0 += BINS_PP) {
        const int nb = min(BINS_PP, N_EDGES - c0);
        for (int t = threadIdx.x; t < nb; t += 256)
            cur[t] = part[(size_t)b * N_EDGES + c0 + t];
        __syncthreads();
        for (int i = threadIdx.x; i < CHUNK; i += 256) {
            int e = E[i0 + i];
            int c = e - c0;
            if (c >= 0 && c < nb) {
                int v = V[i0 + i];
                float w = expf(ls[v]);
                int r = atomicAdd(&cur[c], 1);          // LDS atomic
                epairs[eoff[e] + r] = make_int2(v, __float_as_int(w));
            }
        }
        __syncthreads();
    }
}

// ---------------------------------------------------------------------------
// K5b: scatter incidences into node-CSR (nedges[pos] = e). 7 LDS passes.
// ---------------------------------------------------------------------------
__global__ __launch_bounds__(256) void k_scatter_n(
    const int* __restrict__ V, const int* __restrict__ E,
    const int* __restrict__ noff, const int* __restrict__ part,
    int* __restrict__ nedges)
{
    __shared__ int cur[BINS_PP];
    const int b = blockIdx.x;
    const int i0 = b * CHUNK;
    for (int c0 = 0; c0 < N_NODES; c0 += BINS_PP) {
        const int nb = min(BINS_PP, N_NODES - c0);
        for (int t = threadIdx.x; t < nb; t += 256)
            cur[t] = part[(size_t)b * N_NODES + c0 + t];
        __syncthreads();
        for (int i = threadIdx.x; i < CHUNK; i += 256) {
            int v = V[i0 + i];
            int c = v - c0;
            if (c >= 0 && c < nb) {
                int e = E[i0 + i];
                int r = atomicAdd(&cur[c], 1);          // LDS atomic
                nedges[noff[v] + r] = e;
            }
        }
        __syncthreads();
    }
}

// ---------------------------------------------------------------------------
// K6: per-edge aggregation. All 128 threads walk the edge's incidence list
// together (broadcast epairs loads), so every thread redundantly accumulates
// the softmax denominator dsum = sum(w) for free — no atomics, no extra pass.
// Y_v2e[e] = elu( (sum w_i * X_feat[v_i]) / dsum ); emsg = [Y | S].
// ---------------------------------------------------------------------------
__global__ __launch_bounds__(128) void k_edge_agg(
    const int2* __restrict__ epairs, const int* __restrict__ eoff,
    const float* __restrict__ Xfeat, const float* __restrict__ S,
    float* __restrict__ emsg)
{
    const int e = blockIdx.x;
    const int d = threadIdx.x;      // 0..127
    const int beg = eoff[e], end = eoff[e + 1];
    float acc = 0.f, dsum = 0.f;
    int j = beg;
    for (; j + 1 < end; j += 2) {
        int2 p0 = epairs[j];
        int2 p1 = epairs[j + 1];
        float w0 = __int_as_float(p0.y), w1 = __int_as_float(p1.y);
        float x0 = Xfeat[(size_t)p0.x * D + d];
        float x1 = Xfeat[(size_t)p1.x * D + d];
        dsum += w0 + w1;
        acc = fmaf(w0, x0, acc);
        acc = fmaf(w1, x1, acc);
    }
    if (j < end) {
        int2 p0 = epairs[j];
        float w0 = __int_as_float(p0.y);
        dsum += w0;
        acc = fmaf(w0, Xfeat[(size_t)p0.x * D + d], acc);
    }
    float y = (end > beg) ? acc * (1.f / dsum) : 0.f;
    y = (y > 0.f) ? y : expm1f(y);
    emsg[(size_t)e * (D + STAR) + d] = y;
    if (d < STAR) emsg[(size_t)e * (D + STAR) + D + d] = S[(size_t)e * STAR + d];
}

// ---------------------------------------------------------------------------
// K7: edge GEMM: Y = e_msg @ Wt^T + Wt_b.  M=20000, N=128, K=192.
// ---------------------------------------------------------------------------
__global__ __launch_bounds__(256) void k_edge_gemm(
    const float* __restrict__ A, const float* __restrict__ Wt,
    const float* __restrict__ Wtb, float* __restrict__ Y)
{
    __shared__ float As[BK][BM + 4];
    __shared__ float Bs[BK][BN + 4];
    const int KDIM = D + STAR;   // 192
    const int tid = threadIdx.x;
    const int bm = blockIdx.x * BM;
    const int bn = blockIdx.y * BN;        // 0,64
    const int lr = tid >> 2;
    const int lk = (tid & 3) * 4;
    const int tx = tid & 15, ty = tid >> 4;

    float acc[4][4] = {};

    for (int k0 = 0; k0 < KDIM; k0 += BK) {
        float4 av = make_float4(0.f, 0.f, 0.f, 0.f);
        int row = bm + lr;
        if (row < N_EDGES)
            av = *(const float4*)(A + (size_t)row * KDIM + k0 + lk);
        As[lk + 0][lr] = av.x; As[lk + 1][lr] = av.y;
        As[lk + 2][lr] = av.z; As[lk + 3][lr] = av.w;
        int dd = bn + lr;   // < 128 always
        float4 bv = *(const float4*)(Wt + (size_t)dd * KDIM + k0 + lk);
        Bs[lk + 0][lr] = bv.x; Bs[lk + 1][lr] = bv.y;
        Bs[lk + 2][lr] = bv.z; Bs[lk + 3][lr] = bv.w;
        __syncthreads();
        #pragma unroll
        for (int kk = 0; kk < BK; ++kk) {
            float4 af = *(const float4*)&As[kk][ty * 4];
            float4 bf = *(const float4*)&Bs[kk][tx * 4];
            float a[4] = {af.x, af.y, af.z, af.w};
            float b[4] = {bf.x, bf.y, bf.z, bf.w};
            #pragma unroll
            for (int r = 0; r < 4; ++r)
                #pragma unroll
                for (int c = 0; c < 4; ++c)
                    acc[r][c] = fmaf(a[r], b[c], acc[r][c]);
        }
        __syncthreads();
    }

    const int gcol = bn + tx * 4;
    float4 bb = *(const float4*)(Wtb + gcol);
    #pragma unroll
    for (int r = 0; r < 4; ++r) {
        int row = bm + ty * 4 + r;
        if (row < N_EDGES) {
            float4 o = make_float4(acc[r][0] + bb.x, acc[r][1] + bb.y,
                                   acc[r][2] + bb.z, acc[r][3] + bb.w);
            *(float4*)(Y + (size_t)row * D + gcol) = o;
        }
    }
}

// ---------------------------------------------------------------------------
// K8: per-node aggregation: out[v] = elu( (sum_j Y[e_j]) / max(cnt,1) ) + out[v]
// (out already holds X_init).  One 128-thread block per node.
// ---------------------------------------------------------------------------
__global__ __launch_bounds__(128) void k_node_agg(
    const int* __restrict__ nedges, const int* __restrict__ noff,
    const float* __restrict__ Y, float* __restrict__ out)
{
    const int v = blockIdx.x;
    const int d = threadIdx.x;
    const int beg = noff[v], end = noff[v + 1];
    float acc = 0.f;
    int j = beg;
    for (; j + 1 < end; j += 2) {
        int e0 = nedges[j], e1 = nedges[j + 1];
        acc += Y[(size_t)e0 * D + d];
        acc += Y[(size_t)e1 * D + d];
    }
    if (j < end) acc += Y[(size_t)nedges[j] * D + d];
    int cnt = end - beg;
    float xm = acc / (float)max(cnt, 1);
    xm = (xm > 0.f) ? xm : expm1f(xm);
    size_t o = (size_t)v * D + d;
    out[o] = xm + out[o];
}

// ---------------------------------------------------------------------------
extern "C" void kernel_launch(void* const* d_in, const int* in_sizes, int n_in,
                              void* d_out, int out_size, void* d_ws, size_t ws_size,
                              hipStream_t stream)
{
    const float* X    = (const float*)d_in[0];
    const int*   V    = (const int*)  d_in[1];
    const int*   E    = (const int*)  d_in[2];
    const float* S    = (const float*)d_in[3];
    const float* Wx_w = (const float*)d_in[4];
    const float* Wx_b = (const float*)d_in[5];
    const float* Wv_w = (const float*)d_in[6];
    const float* Wv_b = (const float*)d_in[7];
    const float* a_w  = (const float*)d_in[8];
    const float* Wt_w = (const float*)d_in[9];
    const float* Wt_b = (const float*)d_in[10];
    float* out = (float*)d_out;

    char* p = (char*)d_ws;
    auto take = [&](size_t bytes) -> char* {
        char* r = p;
        p += (bytes + 255) & ~(size_t)255;
        return r;
    };

    float* Xfeat  = (float*)take((size_t)N_NODES * D * 4);
    float* ls     = (float*)take((size_t)N_NODES * 4);
    int*   part_e = (int*)  take((size_t)NBLK * N_EDGES * 4);
    int*   part_n = (int*)  take((size_t)NBLK * N_NODES * 4);
    int*   tot_e  = (int*)  take((size_t)N_EDGES * 4);
    int*   tot_n  = (int*)  take((size_t)N_NODES * 4);
    int*   eoff   = (int*)  take((size_t)(N_EDGES + 1) * 4);
    int*   noff   = (int*)  take((size_t)(N_NODES + 1) * 4);
    int2*  epairs = (int2*) take((size_t)NNZ * 8);
    int*   nedges = (int*)  take((size_t)NNZ * 4);
    float* emsg   = (float*)take((size_t)N_EDGES * (D + STAR) * 4);
    float* Y      = (float*)take((size_t)N_EDGES * D * 4);

    dim3 g1((N_NODES + BM - 1) / BM, 4);
    k_node_gemm<<<g1, 256, 0, stream>>>(X, Wx_w, Wx_b, Wv_w, Wv_b, out, Xfeat);

    k_score<<<(N_NODES + 3) / 4, 256, 0, stream>>>(Xfeat, a_w, ls);

    k_part<<<NBLK, 256, 0, stream>>>(E, N_EDGES, part_e);
    k_part<<<NBLK, 256, 0, stream>>>(V, N_NODES, part_n);

    k_tot_base<<<(N_EDGES + 255) / 256, 256, 0, stream>>>(part_e, N_EDGES, tot_e);
    k_tot_base<<<(N_NODES + 255) / 256, 256, 0, stream>>>(part_n, N_NODES, tot_n);

    k_scan<<<1, 1024, 0, stream>>>(tot_e, eoff, N_EDGES);
    k_scan<<<1, 1024, 0, stream>>>(tot_n, noff, N_NODES);

    k_scatter_e<<<NBLK, 256, 0, stream>>>(V, E, ls, eoff, part_e, epairs);
    k_scatter_n<<<NBLK, 256, 0, stream>>>(V, E, noff, part_n, nedges);

    k_edge_agg<<<N_EDGES, 128, 0, stream>>>(epairs, eoff, Xfeat, S, emsg);

    dim3 g6((N_EDGES + BM - 1) / BM, 2);
    k_edge_gemm<<<g6, 256, 0, stream>>>(emsg, Wt_w, Wt_b, Y);

    k_node_agg<<<N_NODES, 128, 0, stream>>>(nedges, noff, Y, out);
}

// Round 3
// 775.837 us; speedup vs baseline: 1.6011x; 1.6011x over previous
//
#include <hip/hip_runtime.h>
#include <hip/hip_bf16.h>

#define N_NODES 100000
#define N_EDGES 20000
#define NNZ     1600000
#define D       128
#define STAR    64
#define NEG_SLOPE 0.2f

// edge counting-sort partition
#define NBLK_E  200         // chunks
#define CHUNK_E 8000        // NNZ / NBLK_E
#define BINS_E  10000       // bins per LDS pass (40 KB int), 2 passes

// ---------------------------------------------------------------------------
// K1: fused node GEMM:  [X_init | X_feat] = X @ [Wx^T | Wv^T] + bias
// ---------------------------------------------------------------------------
#define BM 64
#define BN 64
#define BK 16

__global__ __launch_bounds__(256) void k_node_gemm(
    const float* __restrict__ X,
    const float* __restrict__ Wx, const float* __restrict__ Wxb,
    const float* __restrict__ Wv, const float* __restrict__ Wvb,
    float* __restrict__ Xinit, float* __restrict__ Xfeat)
{
    __shared__ float As[BK][BM + 4];
    __shared__ float Bs[BK][BN + 4];
    const int tid = threadIdx.x;
    const int bm = blockIdx.x * BM;
    const int bn = blockIdx.y * BN;        // 0,64,128,192
    const int lr = tid >> 2;
    const int lk = (tid & 3) * 4;
    const int tx = tid & 15, ty = tid >> 4;

    float acc[4][4] = {};

    for (int k0 = 0; k0 < D; k0 += BK) {
        float4 av = make_float4(0.f, 0.f, 0.f, 0.f);
        int node = bm + lr;
        if (node < N_NODES)
            av = *(const float4*)(X + (size_t)node * D + k0 + lk);
        As[lk + 0][lr] = av.x; As[lk + 1][lr] = av.y;
        As[lk + 2][lr] = av.z; As[lk + 3][lr] = av.w;
        int dd = bn + lr;
        const float* wsrc = (dd < D) ? (Wx + (size_t)dd * D)
                                     : (Wv + (size_t)(dd - D) * D);
        float4 bv = *(const float4*)(wsrc + k0 + lk);
        Bs[lk + 0][lr] = bv.x; Bs[lk + 1][lr] = bv.y;
        Bs[lk + 2][lr] = bv.z; Bs[lk + 3][lr] = bv.w;
        __syncthreads();
        #pragma unroll
        for (int kk = 0; kk < BK; ++kk) {
            float4 af = *(const float4*)&As[kk][ty * 4];
            float4 bf = *(const float4*)&Bs[kk][tx * 4];
            float a[4] = {af.x, af.y, af.z, af.w};
            float b[4] = {bf.x, bf.y, bf.z, bf.w};
            #pragma unroll
            for (int r = 0; r < 4; ++r)
                #pragma unroll
                for (int c = 0; c < 4; ++c)
                    acc[r][c] = fmaf(a[r], b[c], acc[r][c]);
        }
        __syncthreads();
    }

    const int gcol = bn + tx * 4;
    const bool isInit = (gcol < D);
    const int cc = isInit ? gcol : (gcol - D);
    const float* bias = isInit ? Wxb : Wvb;
    float* dst = isInit ? Xinit : Xfeat;
    float4 bb = *(const float4*)(bias + cc);
    #pragma unroll
    for (int r = 0; r < 4; ++r) {
        int node = bm + ty * 4 + r;
        if (node < N_NODES) {
            float4 o = make_float4(acc[r][0] + bb.x, acc[r][1] + bb.y,
                                   acc[r][2] + bb.z, acc[r][3] + bb.w);
            *(float4*)(dst + (size_t)node * D + cc) = o;
        }
    }
}

// ---------------------------------------------------------------------------
// K2: score[n] = leaky_relu(X_feat[n,:] . a_w)  — one wave per node
// ---------------------------------------------------------------------------
__global__ __launch_bounds__(256) void k_score(
    const float* __restrict__ Xfeat, const float* __restrict__ aw,
    float* __restrict__ ls)
{
    const int wave = threadIdx.x >> 6, lane = threadIdx.x & 63;
    const int node = blockIdx.x * 4 + wave;
    if (node >= N_NODES) return;
    float2 x = *(const float2*)(Xfeat + (size_t)node * D + lane * 2);
    float2 a = *(const float2*)(aw + lane * 2);
    float s = x.x * a.x + x.y * a.y;
    #pragma unroll
    for (int off = 32; off > 0; off >>= 1) s += __shfl_down(s, off, 64);
    if (lane == 0) ls[node] = (s > 0.f) ? s : NEG_SLOPE * s;
}

// ---------------------------------------------------------------------------
// K3: edge histogram + within-(block,bin) rank via LDS atomics ONLY.
// Grid (NBLK_E, 2): block (b,p) processes chunk b, bins [p*BINS_E, ...).
// atomicAdd's return value IS the rank -> re[i] (ushort).
// ---------------------------------------------------------------------------
__global__ __launch_bounds__(256) void k_part_e(
    const int* __restrict__ E, int* __restrict__ part,
    unsigned short* __restrict__ re)
{
    __shared__ int h[BINS_E];
    const int b = blockIdx.x;
    const int c0 = blockIdx.y * BINS_E;
    const int i0 = b * CHUNK_E;
    for (int t = threadIdx.x; t < BINS_E; t += 256) h[t] = 0;
    __syncthreads();
    for (int i = threadIdx.x; i < CHUNK_E; i += 256) {
        int c = E[i0 + i] - c0;
        if (c >= 0 && c < BINS_E) {
            int r = atomicAdd(&h[c], 1);            // LDS atomic, returns rank
            re[i0 + i] = (unsigned short)r;
        }
    }
    __syncthreads();
    for (int t = threadIdx.x; t < BINS_E; t += 256)
        part[(size_t)b * N_EDGES + c0 + t] = h[t];
}

// ---------------------------------------------------------------------------
// K4: node rank via ONE global atomic per incidence (returns rank).
// Also precomputes w = exp(leaky_score[v]) here (latency hidden behind the
// atomic anyway) so the scatter/agg stages stay gather-free.
// ---------------------------------------------------------------------------
__global__ __launch_bounds__(256) void k_rank_n(
    const int* __restrict__ V, const float* __restrict__ ls,
    int* __restrict__ nhist, unsigned short* __restrict__ rn,
    float* __restrict__ warr)
{
    int i = blockIdx.x * 256 + threadIdx.x;
    if (i >= NNZ) return;
    int v = V[i];
    int r = atomicAdd(nhist + v, 1);                // device atomic (rank)
    rn[i] = (unsigned short)r;
    warr[i] = expf(ls[v]);
}

// ---------------------------------------------------------------------------
// K5: per-bin exclusive prefix over edge chunks; emits per-bin totals.
// ---------------------------------------------------------------------------
__global__ __launch_bounds__(256) void k_tot_e(
    int* __restrict__ part, int* __restrict__ tot)
{
    int bin = blockIdx.x * 256 + threadIdx.x;
    if (bin >= N_EDGES) return;
    int run = 0;
    for (int b = 0; b < NBLK_E; ++b) {
        size_t idx = (size_t)b * N_EDGES + bin;
        int v = part[idx];
        part[idx] = run;
        run += v;
    }
    tot[bin] = run;
}

// ---------------------------------------------------------------------------
// Single-block exclusive scan, int4 phase-1. off[n] = total.
// ---------------------------------------------------------------------------
__global__ __launch_bounds__(1024) void k_scan(
    const int* __restrict__ cnt, int* __restrict__ off, int n)
{
    __shared__ int sums[1024];
    const int tid = threadIdx.x;
    const int chunk = (((n + 1023) >> 10) + 3) & ~3;    // multiple of 4
    const int start = tid * chunk;
    int s = 0;
    if (start + chunk <= n) {
        const int4* p4 = (const int4*)(cnt + start);
        #pragma unroll 4
        for (int j = 0; j < chunk / 4; ++j) {
            int4 v = p4[j];
            s += v.x + v.y + v.z + v.w;
        }
    } else {
        for (int i = start; i < n; ++i) s += cnt[i];
    }
    sums[tid] = s;
    __syncthreads();
    for (int d = 1; d < 1024; d <<= 1) {
        int mine = sums[tid];
        int other = (tid >= d) ? sums[tid - d] : 0;
        __syncthreads();
        sums[tid] = mine + other;
        __syncthreads();
    }
    int run = (tid > 0) ? sums[tid - 1] : 0;
    const int end = min(start + chunk, n);
    for (int i = start; i < end; ++i) { off[i] = run; run += cnt[i]; }
    if (tid == 1023) off[n] = sums[1023];
}

// ---------------------------------------------------------------------------
// K6: edge scatter, NO atomics. LDS base = per-chunk prefix + eoff (both
// coalesced at pass start); position = base[bin] + stored rank.
// ---------------------------------------------------------------------------
__global__ __launch_bounds__(256) void k_scatter_e(
    const int* __restrict__ V, const int* __restrict__ E,
    const float* __restrict__ warr, const unsigned short* __restrict__ re,
    const int* __restrict__ eoff, const int* __restrict__ part,
    int2* __restrict__ epairs)
{
    __shared__ int base[BINS_E];
    const int b = blockIdx.x;
    const int c0 = blockIdx.y * BINS_E;
    const int i0 = b * CHUNK_E;
    for (int t = threadIdx.x; t < BINS_E; t += 256)
        base[t] = part[(size_t)b * N_EDGES + c0 + t] + eoff[c0 + t];
    __syncthreads();
    for (int i = threadIdx.x; i < CHUNK_E; i += 256) {
        int e = E[i0 + i];
        int c = e - c0;
        if (c >= 0 && c < BINS_E) {
            int v = V[i0 + i];
            float w = warr[i0 + i];
            epairs[base[c] + re[i0 + i]] = make_int2(v, __float_as_int(w));
        }
    }
}

// ---------------------------------------------------------------------------
// K7: node scatter, NO atomics, flat grid: pos = noff[V[i]] + rn[i].
// ---------------------------------------------------------------------------
__global__ __launch_bounds__(256) void k_scatter_n(
    const int* __restrict__ V, const int* __restrict__ E,
    const unsigned short* __restrict__ rn, const int* __restrict__ noff,
    int* __restrict__ nedges)
{
    int i = blockIdx.x * 256 + threadIdx.x;
    if (i >= NNZ) return;
    nedges[noff[V[i]] + rn[i]] = E[i];
}

// ---------------------------------------------------------------------------
// K8: per-edge aggregation; softmax denominator accumulated for free.
// ---------------------------------------------------------------------------
__global__ __launch_bounds__(128) void k_edge_agg(
    const int2* __restrict__ epairs, const int* __restrict__ eoff,
    const float* __restrict__ Xfeat, const float* __restrict__ S,
    float* __restrict__ emsg)
{
    const int e = blockIdx.x;
    const int d = threadIdx.x;      // 0..127
    const int beg = eoff[e], end = eoff[e + 1];
    float acc = 0.f, dsum = 0.f;
    int j = beg;
    for (; j + 1 < end; j += 2) {
        int2 p0 = epairs[j];
        int2 p1 = epairs[j + 1];
        float w0 = __int_as_float(p0.y), w1 = __int_as_float(p1.y);
        float x0 = Xfeat[(size_t)p0.x * D + d];
        float x1 = Xfeat[(size_t)p1.x * D + d];
        dsum += w0 + w1;
        acc = fmaf(w0, x0, acc);
        acc = fmaf(w1, x1, acc);
    }
    if (j < end) {
        int2 p0 = epairs[j];
        float w0 = __int_as_float(p0.y);
        dsum += w0;
        acc = fmaf(w0, Xfeat[(size_t)p0.x * D + d], acc);
    }
    float y = (end > beg) ? acc * (1.f / dsum) : 0.f;
    y = (y > 0.f) ? y : expm1f(y);
    emsg[(size_t)e * (D + STAR) + d] = y;
    if (d < STAR) emsg[(size_t)e * (D + STAR) + D + d] = S[(size_t)e * STAR + d];
}

// ---------------------------------------------------------------------------
// K9: edge GEMM: Y = e_msg @ Wt^T + Wt_b.  M=20000, N=128, K=192.
// ---------------------------------------------------------------------------
__global__ __launch_bounds__(256) void k_edge_gemm(
    const float* __restrict__ A, const float* __restrict__ Wt,
    const float* __restrict__ Wtb, float* __restrict__ Y)
{
    __shared__ float As[BK][BM + 4];
    __shared__ float Bs[BK][BN + 4];
    const int KDIM = D + STAR;   // 192
    const int tid = threadIdx.x;
    const int bm = blockIdx.x * BM;
    const int bn = blockIdx.y * BN;        // 0,64
    const int lr = tid >> 2;
    const int lk = (tid & 3) * 4;
    const int tx = tid & 15, ty = tid >> 4;

    float acc[4][4] = {};

    for (int k0 = 0; k0 < KDIM; k0 += BK) {
        float4 av = make_float4(0.f, 0.f, 0.f, 0.f);
        int row = bm + lr;
        if (row < N_EDGES)
            av = *(const float4*)(A + (size_t)row * KDIM + k0 + lk);
        As[lk + 0][lr] = av.x; As[lk + 1][lr] = av.y;
        As[lk + 2][lr] = av.z; As[lk + 3][lr] = av.w;
        int dd = bn + lr;   // < 128 always
        float4 bv = *(const float4*)(Wt + (size_t)dd * KDIM + k0 + lk);
        Bs[lk + 0][lr] = bv.x; Bs[lk + 1][lr] = bv.y;
        Bs[lk + 2][lr] = bv.z; Bs[lk + 3][lr] = bv.w;
        __syncthreads();
        #pragma unroll
        for (int kk = 0; kk < BK; ++kk) {
            float4 af = *(const float4*)&As[kk][ty * 4];
            float4 bf = *(const float4*)&Bs[kk][tx * 4];
            float a[4] = {af.x, af.y, af.z, af.w};
            float b[4] = {bf.x, bf.y, bf.z, bf.w};
            #pragma unroll
            for (int r = 0; r < 4; ++r)
                #pragma unroll
                for (int c = 0; c < 4; ++c)
                    acc[r][c] = fmaf(a[r], b[c], acc[r][c]);
        }
        __syncthreads();
    }

    const int gcol = bn + tx * 4;
    float4 bb = *(const float4*)(Wtb + gcol);
    #pragma unroll
    for (int r = 0; r < 4; ++r) {
        int row = bm + ty * 4 + r;
        if (row < N_EDGES) {
            float4 o = make_float4(acc[r][0] + bb.x, acc[r][1] + bb.y,
                                   acc[r][2] + bb.z, acc[r][3] + bb.w);
            *(float4*)(Y + (size_t)row * D + gcol) = o;
        }
    }
}

// ---------------------------------------------------------------------------
// K10: per-node aggregation: out[v] = elu(mean_j Y[e_j]) + out[v]
// ---------------------------------------------------------------------------
__global__ __launch_bounds__(128) void k_node_agg(
    const int* __restrict__ nedges, const int* __restrict__ noff,
    const float* __restrict__ Y, float* __restrict__ out)
{
    const int v = blockIdx.x;
    const int d = threadIdx.x;
    const int beg = noff[v], end = noff[v + 1];
    float acc = 0.f;
    int j = beg;
    for (; j + 1 < end; j += 2) {
        int e0 = nedges[j], e1 = nedges[j + 1];
        acc += Y[(size_t)e0 * D + d];
        acc += Y[(size_t)e1 * D + d];
    }
    if (j < end) acc += Y[(size_t)nedges[j] * D + d];
    int cnt = end - beg;
    float xm = acc / (float)max(cnt, 1);
    xm = (xm > 0.f) ? xm : expm1f(xm);
    size_t o = (size_t)v * D + d;
    out[o] = xm + out[o];
}

// ---------------------------------------------------------------------------
extern "C" void kernel_launch(void* const* d_in, const int* in_sizes, int n_in,
                              void* d_out, int out_size, void* d_ws, size_t ws_size,
                              hipStream_t stream)
{
    const float* X    = (const float*)d_in[0];
    const int*   V    = (const int*)  d_in[1];
    const int*   E    = (const int*)  d_in[2];
    const float* S    = (const float*)d_in[3];
    const float* Wx_w = (const float*)d_in[4];
    const float* Wx_b = (const float*)d_in[5];
    const float* Wv_w = (const float*)d_in[6];
    const float* Wv_b = (const float*)d_in[7];
    const float* a_w  = (const float*)d_in[8];
    const float* Wt_w = (const float*)d_in[9];
    const float* Wt_b = (const float*)d_in[10];
    float* out = (float*)d_out;

    char* p = (char*)d_ws;
    auto take = [&](size_t bytes) -> char* {
        char* r = p;
        p += (bytes + 255) & ~(size_t)255;
        return r;
    };

    float* Xfeat  = (float*)take((size_t)N_NODES * D * 4);
    float* ls     = (float*)take((size_t)N_NODES * 4);
    int*   part_e = (int*)  take((size_t)NBLK_E * N_EDGES * 4);
    int*   tot_e  = (int*)  take((size_t)N_EDGES * 4);
    int*   nhist  = (int*)  take((size_t)N_NODES * 4);
    int*   eoff   = (int*)  take((size_t)(N_EDGES + 1) * 4);
    int*   noff   = (int*)  take((size_t)(N_NODES + 1) * 4);
    unsigned short* re = (unsigned short*)take((size_t)NNZ * 2);
    unsigned short* rn = (unsigned short*)take((size_t)NNZ * 2);
    float* warr   = (float*)take((size_t)NNZ * 4);
    int2*  epairs = (int2*) take((size_t)NNZ * 8);
    int*   nedges = (int*)  take((size_t)NNZ * 4);
    float* emsg   = (float*)take((size_t)N_EDGES * (D + STAR) * 4);
    float* Y      = (float*)take((size_t)N_EDGES * D * 4);

    hipMemsetAsync(nhist, 0, (size_t)N_NODES * 4, stream);

    dim3 g1((N_NODES + BM - 1) / BM, 4);
    k_node_gemm<<<g1, 256, 0, stream>>>(X, Wx_w, Wx_b, Wv_w, Wv_b, out, Xfeat);

    k_score<<<(N_NODES + 3) / 4, 256, 0, stream>>>(Xfeat, a_w, ls);

    k_part_e<<<dim3(NBLK_E, 2), 256, 0, stream>>>(E, part_e, re);

    k_rank_n<<<(NNZ + 255) / 256, 256, 0, stream>>>(V, ls, nhist, rn, warr);

    k_tot_e<<<(N_EDGES + 255) / 256, 256, 0, stream>>>(part_e, tot_e);

    k_scan<<<1, 1024, 0, stream>>>(tot_e, eoff, N_EDGES);
    k_scan<<<1, 1024, 0, stream>>>(nhist, noff, N_NODES);

    k_scatter_e<<<dim3(NBLK_E, 2), 256, 0, stream>>>(V, E, warr, re, eoff,
                                                     part_e, epairs);
    k_scatter_n<<<(NNZ + 255) / 256, 256, 0, stream>>>(V, E, rn, noff, nedges);

    k_edge_agg<<<N_EDGES, 128, 0, stream>>>(epairs, eoff, Xfeat, S, emsg);

    dim3 g6((N_EDGES + BM - 1) / BM, 2);
    k_edge_gemm<<<g6, 256, 0, stream>>>(emsg, Wt_w, Wt_b, Y);

    k_node_agg<<<N_NODES, 128, 0, stream>>>(nedges, noff, Y, out);
}

// Round 4
// 648.364 us; speedup vs baseline: 1.9159x; 1.1966x over previous
//
#include <hip/hip_runtime.h>
#include <hip/hip_bf16.h>

#define N_NODES 100000
#define N_EDGES 20000
#define NNZ     1600000
#define D       128
#define STAR    64
#define NEG_SLOPE 0.2f

// edge counting-sort partition
#define NBLK_E  200         // chunks
#define CHUNK_E 8000        // NNZ / NBLK_E
#define BINS_E  10000       // bins per LDS pass (40 KB int), 2 passes

// multi-block scan: 256 threads x 16 elements
#define SCC 16
#define SC_PER_BLOCK (256 * SCC)   // 4096
#define SC_NBLK(n) (((n) + SC_PER_BLOCK - 1) / SC_PER_BLOCK)

// ---------------------------------------------------------------------------
// K1: fused node GEMM:  [X_init | X_feat] = X @ [Wx^T | Wv^T] + bias
// ---------------------------------------------------------------------------
#define BM 64
#define BN 64
#define BK 16

__global__ __launch_bounds__(256) void k_node_gemm(
    const float* __restrict__ X,
    const float* __restrict__ Wx, const float* __restrict__ Wxb,
    const float* __restrict__ Wv, const float* __restrict__ Wvb,
    float* __restrict__ Xinit, float* __restrict__ Xfeat)
{
    __shared__ float As[BK][BM + 4];
    __shared__ float Bs[BK][BN + 4];
    const int tid = threadIdx.x;
    const int bm = blockIdx.x * BM;
    const int bn = blockIdx.y * BN;        // 0,64,128,192
    const int lr = tid >> 2;
    const int lk = (tid & 3) * 4;
    const int tx = tid & 15, ty = tid >> 4;

    float acc[4][4] = {};

    for (int k0 = 0; k0 < D; k0 += BK) {
        float4 av = make_float4(0.f, 0.f, 0.f, 0.f);
        int node = bm + lr;
        if (node < N_NODES)
            av = *(const float4*)(X + (size_t)node * D + k0 + lk);
        As[lk + 0][lr] = av.x; As[lk + 1][lr] = av.y;
        As[lk + 2][lr] = av.z; As[lk + 3][lr] = av.w;
        int dd = bn + lr;
        const float* wsrc = (dd < D) ? (Wx + (size_t)dd * D)
                                     : (Wv + (size_t)(dd - D) * D);
        float4 bv = *(const float4*)(wsrc + k0 + lk);
        Bs[lk + 0][lr] = bv.x; Bs[lk + 1][lr] = bv.y;
        Bs[lk + 2][lr] = bv.z; Bs[lk + 3][lr] = bv.w;
        __syncthreads();
        #pragma unroll
        for (int kk = 0; kk < BK; ++kk) {
            float4 af = *(const float4*)&As[kk][ty * 4];
            float4 bf = *(const float4*)&Bs[kk][tx * 4];
            float a[4] = {af.x, af.y, af.z, af.w};
            float b[4] = {bf.x, bf.y, bf.z, bf.w};
            #pragma unroll
            for (int r = 0; r < 4; ++r)
                #pragma unroll
                for (int c = 0; c < 4; ++c)
                    acc[r][c] = fmaf(a[r], b[c], acc[r][c]);
        }
        __syncthreads();
    }

    const int gcol = bn + tx * 4;
    const bool isInit = (gcol < D);
    const int cc = isInit ? gcol : (gcol - D);
    const float* bias = isInit ? Wxb : Wvb;
    float* dst = isInit ? Xinit : Xfeat;
    float4 bb = *(const float4*)(bias + cc);
    #pragma unroll
    for (int r = 0; r < 4; ++r) {
        int node = bm + ty * 4 + r;
        if (node < N_NODES) {
            float4 o = make_float4(acc[r][0] + bb.x, acc[r][1] + bb.y,
                                   acc[r][2] + bb.z, acc[r][3] + bb.w);
            *(float4*)(dst + (size_t)node * D + cc) = o;
        }
    }
}

// ---------------------------------------------------------------------------
// K2: score[n] = leaky_relu(X_feat[n,:] . a_w)  — one wave per node
// ---------------------------------------------------------------------------
__global__ __launch_bounds__(256) void k_score(
    const float* __restrict__ Xfeat, const float* __restrict__ aw,
    float* __restrict__ ls)
{
    const int wave = threadIdx.x >> 6, lane = threadIdx.x & 63;
    const int node = blockIdx.x * 4 + wave;
    if (node >= N_NODES) return;
    float2 x = *(const float2*)(Xfeat + (size_t)node * D + lane * 2);
    float2 a = *(const float2*)(aw + lane * 2);
    float s = x.x * a.x + x.y * a.y;
    #pragma unroll
    for (int off = 32; off > 0; off >>= 1) s += __shfl_down(s, off, 64);
    if (lane == 0) ls[node] = (s > 0.f) ? s : NEG_SLOPE * s;
}

// ---------------------------------------------------------------------------
// K3: edge histogram + within-(block,bin) rank via LDS atomics ONLY.
// ---------------------------------------------------------------------------
__global__ __launch_bounds__(256) void k_part_e(
    const int* __restrict__ E, int* __restrict__ part,
    unsigned short* __restrict__ re)
{
    __shared__ int h[BINS_E];
    const int b = blockIdx.x;
    const int c0 = blockIdx.y * BINS_E;
    const int i0 = b * CHUNK_E;
    for (int t = threadIdx.x; t < BINS_E; t += 256) h[t] = 0;
    __syncthreads();
    for (int i = threadIdx.x; i < CHUNK_E; i += 256) {
        int c = E[i0 + i] - c0;
        if (c >= 0 && c < BINS_E) {
            int r = atomicAdd(&h[c], 1);            // LDS atomic, returns rank
            re[i0 + i] = (unsigned short)r;
        }
    }
    __syncthreads();
    for (int t = threadIdx.x; t < BINS_E; t += 256)
        part[(size_t)b * N_EDGES + c0 + t] = h[t];
}

// ---------------------------------------------------------------------------
// K4: node rank via ONE global atomic per incidence (returns rank).
// ---------------------------------------------------------------------------
__global__ __launch_bounds__(256) void k_rank_n(
    const int* __restrict__ V, const float* __restrict__ ls,
    int* __restrict__ nhist, unsigned short* __restrict__ rn,
    float* __restrict__ warr)
{
    int i = blockIdx.x * 256 + threadIdx.x;
    if (i >= NNZ) return;
    int v = V[i];
    int r = atomicAdd(nhist + v, 1);                // device atomic (rank)
    rn[i] = (unsigned short)r;
    warr[i] = expf(ls[v]);
}

// ---------------------------------------------------------------------------
// K5: per-bin exclusive prefix over edge chunks; emits per-bin totals.
// ---------------------------------------------------------------------------
__global__ __launch_bounds__(256) void k_tot_e(
    int* __restrict__ part, int* __restrict__ tot)
{
    int bin = blockIdx.x * 256 + threadIdx.x;
    if (bin >= N_EDGES) return;
    int run = 0;
    for (int b = 0; b < NBLK_E; ++b) {
        size_t idx = (size_t)b * N_EDGES + bin;
        int v = part[idx];
        part[idx] = run;
        run += v;
    }
    tot[bin] = run;
}

// ---------------------------------------------------------------------------
// Multi-block scan, phase 1: per-block sums. 256 thr x 16 elems (int4).
// ---------------------------------------------------------------------------
__global__ __launch_bounds__(256) void k_scan_bsum(
    const int* __restrict__ cnt, int* __restrict__ bsum, int n)
{
    __shared__ int red[256];
    const int base = blockIdx.x * SC_PER_BLOCK + threadIdx.x * SCC;
    int s = 0;
    if (base + SCC <= n) {
        const int4* p4 = (const int4*)(cnt + base);
        #pragma unroll
        for (int j = 0; j < SCC / 4; ++j) {
            int4 v = p4[j];
            s += v.x + v.y + v.z + v.w;
        }
    } else {
        for (int i = base; i < n; ++i) s += cnt[i];
    }
    red[threadIdx.x] = s;
    __syncthreads();
    for (int d = 128; d > 0; d >>= 1) {
        if (threadIdx.x < d) red[threadIdx.x] += red[threadIdx.x + d];
        __syncthreads();
    }
    if (threadIdx.x == 0) bsum[blockIdx.x] = red[0];
}

// ---------------------------------------------------------------------------
// Phase 2: single small block turns bsum into exclusive block bases,
// writes total into off[n].  nb <= 1024.
// ---------------------------------------------------------------------------
__global__ __launch_bounds__(1024) void k_scan_bbase(
    int* __restrict__ bsum, int nb, int* __restrict__ off, int n)
{
    __shared__ int sums[1024];
    const int tid = threadIdx.x;
    sums[tid] = (tid < nb) ? bsum[tid] : 0;
    __syncthreads();
    for (int d = 1; d < 1024; d <<= 1) {
        int mine = sums[tid];
        int other = (tid >= d) ? sums[tid - d] : 0;
        __syncthreads();
        sums[tid] = mine + other;
        __syncthreads();
    }
    if (tid < nb) bsum[tid] = (tid > 0) ? sums[tid - 1] : 0;
    if (tid == 0) off[n] = sums[1023];
}

// ---------------------------------------------------------------------------
// Phase 3: per-block exclusive scan + block base -> off[i].
// ---------------------------------------------------------------------------
__global__ __launch_bounds__(256) void k_scan_out(
    const int* __restrict__ cnt, const int* __restrict__ bsum,
    int* __restrict__ off, int n)
{
    __shared__ int tsum[256];
    const int base = blockIdx.x * SC_PER_BLOCK + threadIdx.x * SCC;
    int vals[SCC];
    int s = 0;
    if (base + SCC <= n) {
        const int4* p4 = (const int4*)(cnt + base);
        #pragma unroll
        for (int j = 0; j < SCC / 4; ++j) {
            int4 v = p4[j];
            vals[4 * j + 0] = v.x; vals[4 * j + 1] = v.y;
            vals[4 * j + 2] = v.z; vals[4 * j + 3] = v.w;
            s += v.x + v.y + v.z + v.w;
        }
    } else {
        #pragma unroll
        for (int j = 0; j < SCC; ++j) {
            int i = base + j;
            vals[j] = (i < n) ? cnt[i] : 0;
            s += vals[j];
        }
    }
    tsum[threadIdx.x] = s;
    __syncthreads();
    for (int d = 1; d < 256; d <<= 1) {
        int mine = tsum[threadIdx.x];
        int other = (threadIdx.x >= d) ? tsum[threadIdx.x - d] : 0;
        __syncthreads();
        tsum[threadIdx.x] = mine + other;
        __syncthreads();
    }
    int run = bsum[blockIdx.x] + ((threadIdx.x > 0) ? tsum[threadIdx.x - 1] : 0);
    #pragma unroll
    for (int j = 0; j < SCC; ++j) {
        int i = base + j;
        if (i < n) { off[i] = run; run += vals[j]; }
    }
}

// ---------------------------------------------------------------------------
// K6: edge scatter, NO atomics.
// ---------------------------------------------------------------------------
__global__ __launch_bounds__(256) void k_scatter_e(
    const int* __restrict__ V, const int* __restrict__ E,
    const float* __restrict__ warr, const unsigned short* __restrict__ re,
    const int* __restrict__ eoff, const int* __restrict__ part,
    int2* __restrict__ epairs)
{
    __shared__ int base[BINS_E];
    const int b = blockIdx.x;
    const int c0 = blockIdx.y * BINS_E;
    const int i0 = b * CHUNK_E;
    for (int t = threadIdx.x; t < BINS_E; t += 256)
        base[t] = part[(size_t)b * N_EDGES + c0 + t] + eoff[c0 + t];
    __syncthreads();
    for (int i = threadIdx.x; i < CHUNK_E; i += 256) {
        int e = E[i0 + i];
        int c = e - c0;
        if (c >= 0 && c < BINS_E) {
            int v = V[i0 + i];
            float w = warr[i0 + i];
            epairs[base[c] + re[i0 + i]] = make_int2(v, __float_as_int(w));
        }
    }
}

// ---------------------------------------------------------------------------
// K7: node scatter, NO atomics, flat grid: pos = noff[V[i]] + rn[i].
// ---------------------------------------------------------------------------
__global__ __launch_bounds__(256) void k_scatter_n(
    const int* __restrict__ V, const int* __restrict__ E,
    const unsigned short* __restrict__ rn, const int* __restrict__ noff,
    int* __restrict__ nedges)
{
    int i = blockIdx.x * 256 + threadIdx.x;
    if (i >= NNZ) return;
    nedges[noff[V[i]] + rn[i]] = E[i];
}

// ---------------------------------------------------------------------------
// K8: per-edge aggregation; softmax denominator accumulated for free.
// ---------------------------------------------------------------------------
__global__ __launch_bounds__(128) void k_edge_agg(
    const int2* __restrict__ epairs, const int* __restrict__ eoff,
    const float* __restrict__ Xfeat, const float* __restrict__ S,
    float* __restrict__ emsg)
{
    const int e = blockIdx.x;
    const int d = threadIdx.x;      // 0..127
    const int beg = eoff[e], end = eoff[e + 1];
    float acc = 0.f, dsum = 0.f;
    int j = beg;
    for (; j + 1 < end; j += 2) {
        int2 p0 = epairs[j];
        int2 p1 = epairs[j + 1];
        float w0 = __int_as_float(p0.y), w1 = __int_as_float(p1.y);
        float x0 = Xfeat[(size_t)p0.x * D + d];
        float x1 = Xfeat[(size_t)p1.x * D + d];
        dsum += w0 + w1;
        acc = fmaf(w0, x0, acc);
        acc = fmaf(w1, x1, acc);
    }
    if (j < end) {
        int2 p0 = epairs[j];
        float w0 = __int_as_float(p0.y);
        dsum += w0;
        acc = fmaf(w0, Xfeat[(size_t)p0.x * D + d], acc);
    }
    float y = (end > beg) ? acc * (1.f / dsum) : 0.f;
    y = (y > 0.f) ? y : expm1f(y);
    emsg[(size_t)e * (D + STAR) + d] = y;
    if (d < STAR) emsg[(size_t)e * (D + STAR) + D + d] = S[(size_t)e * STAR + d];
}

// ---------------------------------------------------------------------------
// K9: edge GEMM: Y = e_msg @ Wt^T + Wt_b.  M=20000, N=128, K=192.
// ---------------------------------------------------------------------------
__global__ __launch_bounds__(256) void k_edge_gemm(
    const float* __restrict__ A, const float* __restrict__ Wt,
    const float* __restrict__ Wtb, float* __restrict__ Y)
{
    __shared__ float As[BK][BM + 4];
    __shared__ float Bs[BK][BN + 4];
    const int KDIM = D + STAR;   // 192
    const int tid = threadIdx.x;
    const int bm = blockIdx.x * BM;
    const int bn = blockIdx.y * BN;        // 0,64
    const int lr = tid >> 2;
    const int lk = (tid & 3) * 4;
    const int tx = tid & 15, ty = tid >> 4;

    float acc[4][4] = {};

    for (int k0 = 0; k0 < KDIM; k0 += BK) {
        float4 av = make_float4(0.f, 0.f, 0.f, 0.f);
        int row = bm + lr;
        if (row < N_EDGES)
            av = *(const float4*)(A + (size_t)row * KDIM + k0 + lk);
        As[lk + 0][lr] = av.x; As[lk + 1][lr] = av.y;
        As[lk + 2][lr] = av.z; As[lk + 3][lr] = av.w;
        int dd = bn + lr;   // < 128 always
        float4 bv = *(const float4*)(Wt + (size_t)dd * KDIM + k0 + lk);
        Bs[lk + 0][lr] = bv.x; Bs[lk + 1][lr] = bv.y;
        Bs[lk + 2][lr] = bv.z; Bs[lk + 3][lr] = bv.w;
        __syncthreads();
        #pragma unroll
        for (int kk = 0; kk < BK; ++kk) {
            float4 af = *(const float4*)&As[kk][ty * 4];
            float4 bf = *(const float4*)&Bs[kk][tx * 4];
            float a[4] = {af.x, af.y, af.z, af.w};
            float b[4] = {bf.x, bf.y, bf.z, bf.w};
            #pragma unroll
            for (int r = 0; r < 4; ++r)
                #pragma unroll
                for (int c = 0; c < 4; ++c)
                    acc[r][c] = fmaf(a[r], b[c], acc[r][c]);
        }
        __syncthreads();
    }

    const int gcol = bn + tx * 4;
    float4 bb = *(const float4*)(Wtb + gcol);
    #pragma unroll
    for (int r = 0; r < 4; ++r) {
        int row = bm + ty * 4 + r;
        if (row < N_EDGES) {
            float4 o = make_float4(acc[r][0] + bb.x, acc[r][1] + bb.y,
                                   acc[r][2] + bb.z, acc[r][3] + bb.w);
            *(float4*)(Y + (size_t)row * D + gcol) = o;
        }
    }
}

// ---------------------------------------------------------------------------
// K10: per-node aggregation: out[v] = elu(mean_j Y[e_j]) + out[v]
// ---------------------------------------------------------------------------
__global__ __launch_bounds__(128) void k_node_agg(
    const int* __restrict__ nedges, const int* __restrict__ noff,
    const float* __restrict__ Y, float* __restrict__ out)
{
    const int v = blockIdx.x;
    const int d = threadIdx.x;
    const int beg = noff[v], end = noff[v + 1];
    float acc = 0.f;
    int j = beg;
    for (; j + 1 < end; j += 2) {
        int e0 = nedges[j], e1 = nedges[j + 1];
        acc += Y[(size_t)e0 * D + d];
        acc += Y[(size_t)e1 * D + d];
    }
    if (j < end) acc += Y[(size_t)nedges[j] * D + d];
    int cnt = end - beg;
    float xm = acc / (float)max(cnt, 1);
    xm = (xm > 0.f) ? xm : expm1f(xm);
    size_t o = (size_t)v * D + d;
    out[o] = xm + out[o];
}

// ---------------------------------------------------------------------------
extern "C" void kernel_launch(void* const* d_in, const int* in_sizes, int n_in,
                              void* d_out, int out_size, void* d_ws, size_t ws_size,
                              hipStream_t stream)
{
    const float* X    = (const float*)d_in[0];
    const int*   V    = (const int*)  d_in[1];
    const int*   E    = (const int*)  d_in[2];
    const float* S    = (const float*)d_in[3];
    const float* Wx_w = (const float*)d_in[4];
    const float* Wx_b = (const float*)d_in[5];
    const float* Wv_w = (const float*)d_in[6];
    const float* Wv_b = (const float*)d_in[7];
    const float* a_w  = (const float*)d_in[8];
    const float* Wt_w = (const float*)d_in[9];
    const float* Wt_b = (const float*)d_in[10];
    float* out = (float*)d_out;

    char* p = (char*)d_ws;
    auto take = [&](size_t bytes) -> char* {
        char* r = p;
        p += (bytes + 255) & ~(size_t)255;
        return r;
    };

    float* Xfeat  = (float*)take((size_t)N_NODES * D * 4);
    float* ls     = (float*)take((size_t)N_NODES * 4);
    int*   part_e = (int*)  take((size_t)NBLK_E * N_EDGES * 4);
    int*   tot_e  = (int*)  take((size_t)N_EDGES * 4);
    int*   nhist  = (int*)  take((size_t)N_NODES * 4);
    int*   eoff   = (int*)  take((size_t)(N_EDGES + 1) * 4);
    int*   noff   = (int*)  take((size_t)(N_NODES + 1) * 4);
    int*   bsum_e = (int*)  take((size_t)SC_NBLK(N_EDGES) * 4);
    int*   bsum_n = (int*)  take((size_t)SC_NBLK(N_NODES) * 4);
    unsigned short* re = (unsigned short*)take((size_t)NNZ * 2);
    unsigned short* rn = (unsigned short*)take((size_t)NNZ * 2);
    float* warr   = (float*)take((size_t)NNZ * 4);
    int2*  epairs = (int2*) take((size_t)NNZ * 8);
    int*   nedges = (int*)  take((size_t)NNZ * 4);
    float* emsg   = (float*)take((size_t)N_EDGES * (D + STAR) * 4);
    float* Y      = (float*)take((size_t)N_EDGES * D * 4);

    hipMemsetAsync(nhist, 0, (size_t)N_NODES * 4, stream);

    dim3 g1((N_NODES + BM - 1) / BM, 4);
    k_node_gemm<<<g1, 256, 0, stream>>>(X, Wx_w, Wx_b, Wv_w, Wv_b, out, Xfeat);

    k_score<<<(N_NODES + 3) / 4, 256, 0, stream>>>(Xfeat, a_w, ls);

    k_part_e<<<dim3(NBLK_E, 2), 256, 0, stream>>>(E, part_e, re);

    k_rank_n<<<(NNZ + 255) / 256, 256, 0, stream>>>(V, ls, nhist, rn, warr);

    k_tot_e<<<(N_EDGES + 255) / 256, 256, 0, stream>>>(part_e, tot_e);

    // edge scan (n = 20000, 5 blocks)
    k_scan_bsum<<<SC_NBLK(N_EDGES), 256, 0, stream>>>(tot_e, bsum_e, N_EDGES);
    k_scan_bbase<<<1, 1024, 0, stream>>>(bsum_e, SC_NBLK(N_EDGES), eoff, N_EDGES);
    k_scan_out<<<SC_NBLK(N_EDGES), 256, 0, stream>>>(tot_e, bsum_e, eoff, N_EDGES);

    // node scan (n = 100000, 25 blocks)
    k_scan_bsum<<<SC_NBLK(N_NODES), 256, 0, stream>>>(nhist, bsum_n, N_NODES);
    k_scan_bbase<<<1, 1024, 0, stream>>>(bsum_n, SC_NBLK(N_NODES), noff, N_NODES);
    k_scan_out<<<SC_NBLK(N_NODES), 256, 0, stream>>>(nhist, bsum_n, noff, N_NODES);

    k_scatter_e<<<dim3(NBLK_E, 2), 256, 0, stream>>>(V, E, warr, re, eoff,
                                                     part_e, epairs);
    k_scatter_n<<<(NNZ + 255) / 256, 256, 0, stream>>>(V, E, rn, noff, nedges);

    k_edge_agg<<<N_EDGES, 128, 0, stream>>>(epairs, eoff, Xfeat, S, emsg);

    dim3 g6((N_EDGES + BM - 1) / BM, 2);
    k_edge_gemm<<<g6, 256, 0, stream>>>(emsg, Wt_w, Wt_b, Y);

    k_node_agg<<<N_NODES, 128, 0, stream>>>(nedges, noff, Y, out);
}

// Round 5
// 609.630 us; speedup vs baseline: 2.0377x; 1.0635x over previous
//
#include <hip/hip_runtime.h>
#include <hip/hip_bf16.h>
#include <hip/hip_fp16.h>

#define N_NODES 100000
#define N_EDGES 20000
#define NNZ     1600000
#define D       128
#define STAR    64
#define NEG_SLOPE 0.2f

// edge counting-sort partition
#define NBLK_E  200         // chunks
#define CHUNK_E 8000        // NNZ / NBLK_E
#define BINS_E  10000       // bins per LDS pass (40 KB int), 2 passes

// multi-block scan: 256 threads x 16 elements
#define SCC 16
#define SC_PER_BLOCK (256 * SCC)   // 4096
#define SC_NBLK(n) (((n) + SC_PER_BLOCK - 1) / SC_PER_BLOCK)

// ---------------------------------------------------------------------------
// K1: fused node GEMM:  [X_init | X_feat] = X @ [Wx^T | Wv^T] + bias
// X_init -> fp32 d_out; X_feat -> fp16 ws table (gather payload).
// ---------------------------------------------------------------------------
#define BM 64
#define BN 64
#define BK 16

__global__ __launch_bounds__(256) void k_node_gemm(
    const float* __restrict__ X,
    const float* __restrict__ Wx, const float* __restrict__ Wxb,
    const float* __restrict__ Wv, const float* __restrict__ Wvb,
    float* __restrict__ Xinit, __half* __restrict__ Xf16)
{
    __shared__ float As[BK][BM + 4];
    __shared__ float Bs[BK][BN + 4];
    const int tid = threadIdx.x;
    const int bm = blockIdx.x * BM;
    const int bn = blockIdx.y * BN;        // 0,64,128,192
    const int lr = tid >> 2;
    const int lk = (tid & 3) * 4;
    const int tx = tid & 15, ty = tid >> 4;

    float acc[4][4] = {};

    for (int k0 = 0; k0 < D; k0 += BK) {
        float4 av = make_float4(0.f, 0.f, 0.f, 0.f);
        int node = bm + lr;
        if (node < N_NODES)
            av = *(const float4*)(X + (size_t)node * D + k0 + lk);
        As[lk + 0][lr] = av.x; As[lk + 1][lr] = av.y;
        As[lk + 2][lr] = av.z; As[lk + 3][lr] = av.w;
        int dd = bn + lr;
        const float* wsrc = (dd < D) ? (Wx + (size_t)dd * D)
                                     : (Wv + (size_t)(dd - D) * D);
        float4 bv = *(const float4*)(wsrc + k0 + lk);
        Bs[lk + 0][lr] = bv.x; Bs[lk + 1][lr] = bv.y;
        Bs[lk + 2][lr] = bv.z; Bs[lk + 3][lr] = bv.w;
        __syncthreads();
        #pragma unroll
        for (int kk = 0; kk < BK; ++kk) {
            float4 af = *(const float4*)&As[kk][ty * 4];
            float4 bf = *(const float4*)&Bs[kk][tx * 4];
            float a[4] = {af.x, af.y, af.z, af.w};
            float b[4] = {bf.x, bf.y, bf.z, bf.w};
            #pragma unroll
            for (int r = 0; r < 4; ++r)
                #pragma unroll
                for (int c = 0; c < 4; ++c)
                    acc[r][c] = fmaf(a[r], b[c], acc[r][c]);
        }
        __syncthreads();
    }

    const int gcol = bn + tx * 4;
    const bool isInit = (gcol < D);
    const int cc = isInit ? gcol : (gcol - D);
    const float* bias = isInit ? Wxb : Wvb;
    float4 bb = *(const float4*)(bias + cc);
    #pragma unroll
    for (int r = 0; r < 4; ++r) {
        int node = bm + ty * 4 + r;
        if (node < N_NODES) {
            float4 o = make_float4(acc[r][0] + bb.x, acc[r][1] + bb.y,
                                   acc[r][2] + bb.z, acc[r][3] + bb.w);
            if (isInit) {
                *(float4*)(Xinit + (size_t)node * D + cc) = o;
            } else {
                __half2 h01 = __floats2half2_rn(o.x, o.y);
                __half2 h23 = __floats2half2_rn(o.z, o.w);
                *(__half2*)(Xf16 + (size_t)node * D + cc) = h01;
                *(__half2*)(Xf16 + (size_t)node * D + cc + 2) = h23;
            }
        }
    }
}

// ---------------------------------------------------------------------------
// K2: wexp[n] = exp(leaky_relu(X_feat[n,:] . a_w)) — one wave per node.
// Emitting exp() here makes the scatter stage gather from a 400 KB table.
// ---------------------------------------------------------------------------
__global__ __launch_bounds__(256) void k_score(
    const __half* __restrict__ Xf16, const float* __restrict__ aw,
    float* __restrict__ wexp)
{
    const int wave = threadIdx.x >> 6, lane = threadIdx.x & 63;
    const int node = blockIdx.x * 4 + wave;
    if (node >= N_NODES) return;
    __half2 h = *(const __half2*)(Xf16 + (size_t)node * D + lane * 2);
    float2 x = __half22float2(h);
    float2 a = *(const float2*)(aw + lane * 2);
    float s = x.x * a.x + x.y * a.y;
    #pragma unroll
    for (int off = 32; off > 0; off >>= 1) s += __shfl_down(s, off, 64);
    if (lane == 0) {
        float l = (s > 0.f) ? s : NEG_SLOPE * s;
        wexp[node] = expf(l);
    }
}

// ---------------------------------------------------------------------------
// K3: edge histogram + within-(block,bin) rank via LDS atomics ONLY.
// ---------------------------------------------------------------------------
__global__ __launch_bounds__(256) void k_part_e(
    const int* __restrict__ E, int* __restrict__ part,
    unsigned short* __restrict__ re)
{
    __shared__ int h[BINS_E];
    const int b = blockIdx.x;
    const int c0 = blockIdx.y * BINS_E;
    const int i0 = b * CHUNK_E;
    for (int t = threadIdx.x; t < BINS_E; t += 256) h[t] = 0;
    __syncthreads();
    for (int i = threadIdx.x; i < CHUNK_E; i += 256) {
        int c = E[i0 + i] - c0;
        if (c >= 0 && c < BINS_E) {
            int r = atomicAdd(&h[c], 1);            // LDS atomic, returns rank
            re[i0 + i] = (unsigned short)r;
        }
    }
    __syncthreads();
    for (int t = threadIdx.x; t < BINS_E; t += 256)
        part[(size_t)b * N_EDGES + c0 + t] = h[t];
}

// ---------------------------------------------------------------------------
// K4: node rank via ONE global atomic per incidence (returns rank).
// ---------------------------------------------------------------------------
__global__ __launch_bounds__(256) void k_rank_n(
    const int* __restrict__ V, int* __restrict__ nhist,
    unsigned short* __restrict__ rn)
{
    int i = blockIdx.x * 256 + threadIdx.x;
    if (i >= NNZ) return;
    int r = atomicAdd(nhist + V[i], 1);             // device atomic (rank)
    rn[i] = (unsigned short)r;
}

// ---------------------------------------------------------------------------
// K5: per-bin exclusive prefix over edge chunks; emits per-bin totals.
// ---------------------------------------------------------------------------
__global__ __launch_bounds__(256) void k_tot_e(
    int* __restrict__ part, int* __restrict__ tot)
{
    int bin = blockIdx.x * 256 + threadIdx.x;
    if (bin >= N_EDGES) return;
    int run = 0;
    for (int b = 0; b < NBLK_E; ++b) {
        size_t idx = (size_t)b * N_EDGES + bin;
        int v = part[idx];
        part[idx] = run;
        run += v;
    }
    tot[bin] = run;
}

// ---------------------------------------------------------------------------
// Multi-block scan, phase 1: per-block sums. 256 thr x 16 elems (int4).
// ---------------------------------------------------------------------------
__global__ __launch_bounds__(256) void k_scan_bsum(
    const int* __restrict__ cnt, int* __restrict__ bsum, int n)
{
    __shared__ int red[256];
    const int base = blockIdx.x * SC_PER_BLOCK + threadIdx.x * SCC;
    int s = 0;
    if (base + SCC <= n) {
        const int4* p4 = (const int4*)(cnt + base);
        #pragma unroll
        for (int j = 0; j < SCC / 4; ++j) {
            int4 v = p4[j];
            s += v.x + v.y + v.z + v.w;
        }
    } else {
        for (int i = base; i < n; ++i) s += cnt[i];
    }
    red[threadIdx.x] = s;
    __syncthreads();
    for (int d = 128; d > 0; d >>= 1) {
        if (threadIdx.x < d) red[threadIdx.x] += red[threadIdx.x + d];
        __syncthreads();
    }
    if (threadIdx.x == 0) bsum[blockIdx.x] = red[0];
}

// ---------------------------------------------------------------------------
// Phase 2: single small block turns bsum into exclusive block bases,
// writes total into off[n].  nb <= 1024.
// ---------------------------------------------------------------------------
__global__ __launch_bounds__(1024) void k_scan_bbase(
    int* __restrict__ bsum, int nb, int* __restrict__ off, int n)
{
    __shared__ int sums[1024];
    const int tid = threadIdx.x;
    sums[tid] = (tid < nb) ? bsum[tid] : 0;
    __syncthreads();
    for (int d = 1; d < 1024; d <<= 1) {
        int mine = sums[tid];
        int other = (tid >= d) ? sums[tid - d] : 0;
        __syncthreads();
        sums[tid] = mine + other;
        __syncthreads();
    }
    if (tid < nb) bsum[tid] = (tid > 0) ? sums[tid - 1] : 0;
    if (tid == 0) off[n] = sums[1023];
}

// ---------------------------------------------------------------------------
// Phase 3: per-block exclusive scan + block base -> off[i].
// ---------------------------------------------------------------------------
__global__ __launch_bounds__(256) void k_scan_out(
    const int* __restrict__ cnt, const int* __restrict__ bsum,
    int* __restrict__ off, int n)
{
    __shared__ int tsum[256];
    const int base = blockIdx.x * SC_PER_BLOCK + threadIdx.x * SCC;
    int vals[SCC];
    int s = 0;
    if (base + SCC <= n) {
        const int4* p4 = (const int4*)(cnt + base);
        #pragma unroll
        for (int j = 0; j < SCC / 4; ++j) {
            int4 v = p4[j];
            vals[4 * j + 0] = v.x; vals[4 * j + 1] = v.y;
            vals[4 * j + 2] = v.z; vals[4 * j + 3] = v.w;
            s += v.x + v.y + v.z + v.w;
        }
    } else {
        #pragma unroll
        for (int j = 0; j < SCC; ++j) {
            int i = base + j;
            vals[j] = (i < n) ? cnt[i] : 0;
            s += vals[j];
        }
    }
    tsum[threadIdx.x] = s;
    __syncthreads();
    for (int d = 1; d < 256; d <<= 1) {
        int mine = tsum[threadIdx.x];
        int other = (threadIdx.x >= d) ? tsum[threadIdx.x - d] : 0;
        __syncthreads();
        tsum[threadIdx.x] = mine + other;
        __syncthreads();
    }
    int run = bsum[blockIdx.x] + ((threadIdx.x > 0) ? tsum[threadIdx.x - 1] : 0);
    #pragma unroll
    for (int j = 0; j < SCC; ++j) {
        int i = base + j;
        if (i < n) { off[i] = run; run += vals[j]; }
    }
}

// ---------------------------------------------------------------------------
// K6: edge scatter, NO atomics. w gathered from 400 KB wexp table.
// ---------------------------------------------------------------------------
__global__ __launch_bounds__(256) void k_scatter_e(
    const int* __restrict__ V, const int* __restrict__ E,
    const float* __restrict__ wexp, const unsigned short* __restrict__ re,
    const int* __restrict__ eoff, const int* __restrict__ part,
    int2* __restrict__ epairs)
{
    __shared__ int base[BINS_E];
    const int b = blockIdx.x;
    const int c0 = blockIdx.y * BINS_E;
    const int i0 = b * CHUNK_E;
    for (int t = threadIdx.x; t < BINS_E; t += 256)
        base[t] = part[(size_t)b * N_EDGES + c0 + t] + eoff[c0 + t];
    __syncthreads();
    for (int i = threadIdx.x; i < CHUNK_E; i += 256) {
        int e = E[i0 + i];
        int c = e - c0;
        if (c >= 0 && c < BINS_E) {
            int v = V[i0 + i];
            float w = wexp[v];
            epairs[base[c] + re[i0 + i]] = make_int2(v, __float_as_int(w));
        }
    }
}

// ---------------------------------------------------------------------------
// K7: node scatter, NO atomics, flat grid: pos = noff[V[i]] + rn[i].
// ---------------------------------------------------------------------------
__global__ __launch_bounds__(256) void k_scatter_n(
    const int* __restrict__ V, const int* __restrict__ E,
    const unsigned short* __restrict__ rn, const int* __restrict__ noff,
    int* __restrict__ nedges)
{
    int i = blockIdx.x * 256 + threadIdx.x;
    if (i >= NNZ) return;
    nedges[noff[V[i]] + rn[i]] = E[i];
}

// ---------------------------------------------------------------------------
// K8: per-edge aggregation. ONE WAVE PER EDGE; lane handles 2 dims (half2).
// Softmax denominator accumulated redundantly per lane (free).
// ---------------------------------------------------------------------------
__global__ __launch_bounds__(256) void k_edge_agg(
    const int2* __restrict__ epairs, const int* __restrict__ eoff,
    const __half* __restrict__ Xf16, const float* __restrict__ S,
    float* __restrict__ emsg)
{
    const int wave = threadIdx.x >> 6, lane = threadIdx.x & 63;
    const int e = blockIdx.x * 4 + wave;
    if (e >= N_EDGES) return;
    const int beg = eoff[e], end = eoff[e + 1];
    float ax = 0.f, ay = 0.f, dsum = 0.f;
    int j = beg;
    for (; j + 1 < end; j += 2) {
        int2 p0 = epairs[j];
        int2 p1 = epairs[j + 1];
        float w0 = __int_as_float(p0.y), w1 = __int_as_float(p1.y);
        float2 x0 = __half22float2(*(const __half2*)(Xf16 + (size_t)p0.x * D + lane * 2));
        float2 x1 = __half22float2(*(const __half2*)(Xf16 + (size_t)p1.x * D + lane * 2));
        dsum += w0 + w1;
        ax = fmaf(w0, x0.x, ax); ay = fmaf(w0, x0.y, ay);
        ax = fmaf(w1, x1.x, ax); ay = fmaf(w1, x1.y, ay);
    }
    if (j < end) {
        int2 p0 = epairs[j];
        float w0 = __int_as_float(p0.y);
        float2 x0 = __half22float2(*(const __half2*)(Xf16 + (size_t)p0.x * D + lane * 2));
        dsum += w0;
        ax = fmaf(w0, x0.x, ax); ay = fmaf(w0, x0.y, ay);
    }
    float inv = (end > beg) ? 1.f / dsum : 0.f;
    float y0 = ax * inv, y1 = ay * inv;
    y0 = (y0 > 0.f) ? y0 : expm1f(y0);
    y1 = (y1 > 0.f) ? y1 : expm1f(y1);
    const size_t rb = (size_t)e * (D + STAR);
    *(float2*)(emsg + rb + lane * 2) = make_float2(y0, y1);
    if (lane < 32) {
        float2 s2 = *(const float2*)(S + (size_t)e * STAR + lane * 2);
        *(float2*)(emsg + rb + D + lane * 2) = s2;
    }
}

// ---------------------------------------------------------------------------
// K9: edge GEMM: Y = e_msg @ Wt^T + Wt_b -> fp16 (gather payload).
// M=20000, N=128, K=192.
// ---------------------------------------------------------------------------
__global__ __launch_bounds__(256) void k_edge_gemm(
    const float* __restrict__ A, const float* __restrict__ Wt,
    const float* __restrict__ Wtb, __half* __restrict__ Y16)
{
    __shared__ float As[BK][BM + 4];
    __shared__ float Bs[BK][BN + 4];
    const int KDIM = D + STAR;   // 192
    const int tid = threadIdx.x;
    const int bm = blockIdx.x * BM;
    const int bn = blockIdx.y * BN;        // 0,64
    const int lr = tid >> 2;
    const int lk = (tid & 3) * 4;
    const int tx = tid & 15, ty = tid >> 4;

    float acc[4][4] = {};

    for (int k0 = 0; k0 < KDIM; k0 += BK) {
        float4 av = make_float4(0.f, 0.f, 0.f, 0.f);
        int row = bm + lr;
        if (row < N_EDGES)
            av = *(const float4*)(A + (size_t)row * KDIM + k0 + lk);
        As[lk + 0][lr] = av.x; As[lk + 1][lr] = av.y;
        As[lk + 2][lr] = av.z; As[lk + 3][lr] = av.w;
        int dd = bn + lr;   // < 128 always
        float4 bv = *(const float4*)(Wt + (size_t)dd * KDIM + k0 + lk);
        Bs[lk + 0][lr] = bv.x; Bs[lk + 1][lr] = bv.y;
        Bs[lk + 2][lr] = bv.z; Bs[lk + 3][lr] = bv.w;
        __syncthreads();
        #pragma unroll
        for (int kk = 0; kk < BK; ++kk) {
            float4 af = *(const float4*)&As[kk][ty * 4];
            float4 bf = *(const float4*)&Bs[kk][tx * 4];
            float a[4] = {af.x, af.y, af.z, af.w};
            float b[4] = {bf.x, bf.y, bf.z, bf.w};
            #pragma unroll
            for (int r = 0; r < 4; ++r)
                #pragma unroll
                for (int c = 0; c < 4; ++c)
                    acc[r][c] = fmaf(a[r], b[c], acc[r][c]);
        }
        __syncthreads();
    }

    const int gcol = bn + tx * 4;
    float4 bb = *(const float4*)(Wtb + gcol);
    #pragma unroll
    for (int r = 0; r < 4; ++r) {
        int row = bm + ty * 4 + r;
        if (row < N_EDGES) {
            __half2 h01 = __floats2half2_rn(acc[r][0] + bb.x, acc[r][1] + bb.y);
            __half2 h23 = __floats2half2_rn(acc[r][2] + bb.z, acc[r][3] + bb.w);
            *(__half2*)(Y16 + (size_t)row * D + gcol) = h01;
            *(__half2*)(Y16 + (size_t)row * D + gcol + 2) = h23;
        }
    }
}

// ---------------------------------------------------------------------------
// K10: per-node aggregation. ONE WAVE PER NODE; lane handles 2 dims (half2).
// out[v] = elu(mean_j Y[e_j]) + out[v]   (out holds X_init).
// ---------------------------------------------------------------------------
__global__ __launch_bounds__(256) void k_node_agg(
    const int* __restrict__ nedges, const int* __restrict__ noff,
    const __half* __restrict__ Y16, float* __restrict__ out)
{
    const int wave = threadIdx.x >> 6, lane = threadIdx.x & 63;
    const int v = blockIdx.x * 4 + wave;
    if (v >= N_NODES) return;
    const int beg = noff[v], end = noff[v + 1];
    float ax = 0.f, ay = 0.f;
    int j = beg;
    for (; j + 1 < end; j += 2) {
        int e0 = nedges[j], e1 = nedges[j + 1];
        float2 y0 = __half22float2(*(const __half2*)(Y16 + (size_t)e0 * D + lane * 2));
        float2 y1 = __half22float2(*(const __half2*)(Y16 + (size_t)e1 * D + lane * 2));
        ax += y0.x + y1.x;
        ay += y0.y + y1.y;
    }
    if (j < end) {
        int e0 = nedges[j];
        float2 y0 = __half22float2(*(const __half2*)(Y16 + (size_t)e0 * D + lane * 2));
        ax += y0.x; ay += y0.y;
    }
    int cnt = end - beg;
    float invc = 1.f / (float)max(cnt, 1);
    float x0 = ax * invc, x1 = ay * invc;
    x0 = (x0 > 0.f) ? x0 : expm1f(x0);
    x1 = (x1 > 0.f) ? x1 : expm1f(x1);
    float2* o = (float2*)(out + (size_t)v * D + lane * 2);
    float2 cur = *o;
    *o = make_float2(cur.x + x0, cur.y + x1);
}

// ---------------------------------------------------------------------------
extern "C" void kernel_launch(void* const* d_in, const int* in_sizes, int n_in,
                              void* d_out, int out_size, void* d_ws, size_t ws_size,
                              hipStream_t stream)
{
    const float* X    = (const float*)d_in[0];
    const int*   V    = (const int*)  d_in[1];
    const int*   E    = (const int*)  d_in[2];
    const float* S    = (const float*)d_in[3];
    const float* Wx_w = (const float*)d_in[4];
    const float* Wx_b = (const float*)d_in[5];
    const float* Wv_w = (const float*)d_in[6];
    const float* Wv_b = (const float*)d_in[7];
    const float* a_w  = (const float*)d_in[8];
    const float* Wt_w = (const float*)d_in[9];
    const float* Wt_b = (const float*)d_in[10];
    float* out = (float*)d_out;

    char* p = (char*)d_ws;
    auto take = [&](size_t bytes) -> char* {
        char* r = p;
        p += (bytes + 255) & ~(size_t)255;
        return r;
    };

    __half* Xf16  = (__half*)take((size_t)N_NODES * D * 2);
    float*  wexp  = (float*) take((size_t)N_NODES * 4);
    int*    part_e = (int*)  take((size_t)NBLK_E * N_EDGES * 4);
    int*    tot_e = (int*)   take((size_t)N_EDGES * 4);
    int*    nhist = (int*)   take((size_t)N_NODES * 4);
    int*    eoff  = (int*)   take((size_t)(N_EDGES + 1) * 4);
    int*    noff  = (int*)   take((size_t)(N_NODES + 1) * 4);
    int*    bsum_e = (int*)  take((size_t)SC_NBLK(N_EDGES) * 4);
    int*    bsum_n = (int*)  take((size_t)SC_NBLK(N_NODES) * 4);
    unsigned short* re = (unsigned short*)take((size_t)NNZ * 2);
    unsigned short* rn = (unsigned short*)take((size_t)NNZ * 2);
    int2*   epairs = (int2*) take((size_t)NNZ * 8);
    int*    nedges = (int*)  take((size_t)NNZ * 4);
    float*  emsg  = (float*) take((size_t)N_EDGES * (D + STAR) * 4);
    __half* Y16   = (__half*)take((size_t)N_EDGES * D * 2);

    hipMemsetAsync(nhist, 0, (size_t)N_NODES * 4, stream);

    dim3 g1((N_NODES + BM - 1) / BM, 4);
    k_node_gemm<<<g1, 256, 0, stream>>>(X, Wx_w, Wx_b, Wv_w, Wv_b, out, Xf16);

    k_score<<<(N_NODES + 3) / 4, 256, 0, stream>>>(Xf16, a_w, wexp);

    k_part_e<<<dim3(NBLK_E, 2), 256, 0, stream>>>(E, part_e, re);

    k_rank_n<<<(NNZ + 255) / 256, 256, 0, stream>>>(V, nhist, rn);

    k_tot_e<<<(N_EDGES + 255) / 256, 256, 0, stream>>>(part_e, tot_e);

    // edge scan (n = 20000, 5 blocks)
    k_scan_bsum<<<SC_NBLK(N_EDGES), 256, 0, stream>>>(tot_e, bsum_e, N_EDGES);
    k_scan_bbase<<<1, 1024, 0, stream>>>(bsum_e, SC_NBLK(N_EDGES), eoff, N_EDGES);
    k_scan_out<<<SC_NBLK(N_EDGES), 256, 0, stream>>>(tot_e, bsum_e, eoff, N_EDGES);

    // node scan (n = 100000, 25 blocks)
    k_scan_bsum<<<SC_NBLK(N_NODES), 256, 0, stream>>>(nhist, bsum_n, N_NODES);
    k_scan_bbase<<<1, 1024, 0, stream>>>(bsum_n, SC_NBLK(N_NODES), noff, N_NODES);
    k_scan_out<<<SC_NBLK(N_NODES), 256, 0, stream>>>(nhist, bsum_n, noff, N_NODES);

    k_scatter_e<<<dim3(NBLK_E, 2), 256, 0, stream>>>(V, E, wexp, re, eoff,
                                                     part_e, epairs);
    k_scatter_n<<<(NNZ + 255) / 256, 256, 0, stream>>>(V, E, rn, noff, nedges);

    k_edge_agg<<<(N_EDGES + 3) / 4, 256, 0, stream>>>(epairs, eoff, Xf16, S, emsg);

    dim3 g6((N_EDGES + BM - 1) / BM, 2);
    k_edge_gemm<<<g6, 256, 0, stream>>>(emsg, Wt_w, Wt_b, Y16);

    k_node_agg<<<(N_NODES + 3) / 4, 256, 0, stream>>>(nedges, noff, Y16, out);
}